// Round 1
// baseline (426.565 us; speedup 1.0000x reference)
//
#include <hip/hip_runtime.h>

// Sparse upsample block: up-GEMM -> BN/ReLU -> concat -> sparse conv (27-tap,
// gather form since nbr_dst[t,i] ∈ {i, N2}) -> BN/ReLU -> sparse conv -> BN/ReLU.
// Strategy: bucket voxels by up_kidx (child position) so 32-row wave-tiles have
// <=8 own-cell taps (ballot skip); bf16 MFMA 32x32x16 with pre-packed B frags.

typedef short bf16x8 __attribute__((ext_vector_type(8)));   // 8 bf16 (4 VGPRs)
typedef float f32x16 __attribute__((ext_vector_type(16)));  // 32x32 C/D acc

__device__ __forceinline__ short f2bf(float f) {            // RNE f32->bf16
    unsigned u = __float_as_uint(f);
    u += 0x7fffu + ((u >> 16) & 1u);
    return (short)(u >> 16);
}

// ---------------- pack: weights -> bf16 B-fragment layout; feats1 -> bf16;
// also zeroes counters + stats (runs before everything else). ----------------
// B-frag layout for v_mfma_f32_32x32x16_bf16: lane holds B[k=(lane>>5)*8+j][n=lane&31]
// packed as [mat][kstep][ntile][lane][j] so kernel B loads are lane-coalesced 16B.
__global__ __launch_bounds__(256) void k_pack(
    const float* __restrict__ w_up, const float* __restrict__ w1,
    const float* __restrict__ w2, const float* __restrict__ f1,
    short* __restrict__ wupp, short* __restrict__ w1p,
    short* __restrict__ w2p, short* __restrict__ f1bf,
    int* __restrict__ cnt, float* __restrict__ stats, int n1)
{
    long long gid = (long long)blockIdx.x * blockDim.x + threadIdx.x;
    if (gid < 8) cnt[gid] = 0;
    else if (gid < 8 + 384) stats[gid - 8] = 0.f;
    const long long nup = 65536, nw1 = 221184, nw2 = 110592;
    long long nf1 = (long long)n1 * 128;
    long long total = nup + nw1 + nw2 + nf1;
    long long stride = (long long)gridDim.x * blockDim.x;
    for (long long e0 = gid; e0 < total; e0 += stride) {
        long long e = e0;
        if (e < nup) {
            int j = e & 7, l = (e >> 3) & 63, nt = (e >> 9) & 1, ks = (e >> 10) & 7, k8 = (int)(e >> 13);
            int kk = ks * 16 + (l >> 5) * 8 + j;
            int n = nt * 32 + (l & 31);
            wupp[e] = f2bf(w_up[((size_t)k8 * 128 + kk) * 64 + n]);
        } else if ((e -= nup) < nw1) {
            int j = e & 7, l = (e >> 3) & 63, nt = (e >> 9) & 1, ks = (e >> 10) & 7, t = (int)(e >> 13);
            int kk = ks * 16 + (l >> 5) * 8 + j;
            int n = nt * 32 + (l & 31);
            w1p[e] = f2bf(w1[((size_t)t * 128 + kk) * 64 + n]);
        } else if ((e -= nw1) < nw2) {
            int j = e & 7, l = (e >> 3) & 63, nt = (e >> 9) & 1, ks = (e >> 10) & 3, t = (int)(e >> 12);
            int kk = ks * 16 + (l >> 5) * 8 + j;
            int n = nt * 32 + (l & 31);
            w2p[e] = f2bf(w2[((size_t)t * 64 + kk) * 64 + n]);
        } else {
            e -= nw2;
            f1bf[e] = f2bf(f1[e]);
        }
    }
}

// ---------------- bucket scatter by up_kidx (wave-aggregated atomics) --------
__global__ __launch_bounds__(256) void k_scatter(
    const int* __restrict__ up_kidx, int* __restrict__ cnt,
    int* __restrict__ perm2d, int n2)
{
    int i = blockIdx.x * blockDim.x + threadIdx.x;
    int lane = threadIdx.x & 63;
    int myk = (i < n2) ? up_kidx[i] : -1;
    for (int kk = 0; kk < 8; ++kk) {
        unsigned long long msk = __ballot(myk == kk);
        if (msk == 0ULL) continue;
        int leader = __ffsll(msk) - 1;
        int base = 0;
        if (lane == leader) base = atomicAdd(&cnt[kk], (int)__popcll(msk));
        base = __shfl(base, leader);
        if (myk == kk) {
            int pos = base + (int)__popcll(msk & ((1ULL << lane) - 1ULL));
            perm2d[(size_t)kk * n2 + pos] = i;
        }
    }
}

// map row-tile id -> (bucket k, bucket count ck, local tile lt); 32 rows/tile
__device__ __forceinline__ bool map_tile(const int* __restrict__ cnt, int rt,
                                         int& k, int& ck, int& lt)
{
    int base = 0;
    for (k = 0; k < 8; ++k) {
        int c = cnt[k];
        int tk = (c + 31) >> 5;
        if (rt < base + tk) { ck = c; lt = rt - base; return true; }
        base += tk;
    }
    return false;
}

// epilogue: scatter 32x32 C/D tile (col=lane&31, row=(reg&3)+8*(reg>>2)+4*(lane>>5))
// to y[d,*], accumulate BN sum/sumsq via one atomic pair per channel per wave.
__device__ __forceinline__ void epilogue(const f32x16& acc, int d, int lane, int nt,
                                         float* __restrict__ y,
                                         float* __restrict__ stats, int n2)
{
    int col = lane & 31;
    int half = lane >> 5;
    #pragma unroll
    for (int reg = 0; reg < 16; ++reg) {
        int r = (reg & 3) + 8 * (reg >> 2) + 4 * half;
        int drow = __shfl(d, r);
        if (drow < n2) y[(size_t)drow * 64 + nt * 32 + col] = acc[reg];
    }
    float s0 = 0.f, q0 = 0.f;
    #pragma unroll
    for (int reg = 0; reg < 16; ++reg) { s0 += acc[reg]; q0 += acc[reg] * acc[reg]; }
    s0 += __shfl_xor(s0, 32);
    q0 += __shfl_xor(q0, 32);
    if (lane < 32) {
        atomicAdd(&stats[nt * 32 + col], s0);        // sum
        atomicAdd(&stats[64 + nt * 32 + col], q0);   // sumsq
    }
}

// ---------------- upsample GEMM: yup[i] = feats1[up_src[i]] @ w_up[bucket] ---
__global__ __launch_bounds__(256) void k_up(
    const short* __restrict__ f1bf, const short* __restrict__ wupp,
    const int* __restrict__ up_src, const int* __restrict__ perm2d,
    const int* __restrict__ cnt, float* __restrict__ yup,
    float* __restrict__ stats, int n2)
{
    int wid = blockIdx.x * 4 + (threadIdx.x >> 6);
    int lane = threadIdx.x & 63;
    int nt = wid & 1;
    int rt = wid >> 1;
    int k, ck, lt;
    if (!map_tile(cnt, rt, k, ck, lt)) return;
    int m = lane & 31, half = lane >> 5;
    int slot = lt * 32 + m;
    int d = (slot < ck) ? perm2d[(size_t)k * n2 + slot] : n2;
    bool valid = d < n2;
    int src = valid ? up_src[d] : 0;
    const bf16x8* ar = (const bf16x8*)(f1bf + (size_t)src * 128 + half * 8);
    const bf16x8* bp = (const bf16x8*)wupp + ((size_t)k * 16 + nt) * 64 + lane;
    const bf16x8 zero8 = {0, 0, 0, 0, 0, 0, 0, 0};
    f32x16 acc;
    #pragma unroll
    for (int i = 0; i < 16; ++i) acc[i] = 0.f;
    #pragma unroll
    for (int ks = 0; ks < 8; ++ks) {
        bf16x8 a = valid ? ar[ks * 2] : zero8;       // k-step = 16 elems = 2 units
        bf16x8 b = bp[(size_t)ks * 2 * 64];
        acc = __builtin_amdgcn_mfma_f32_32x32x16_bf16(a, b, acc, 0, 0, 0);
    }
    epilogue(acc, d, lane, nt, yup, stats, n2);
}

// ---------------- sparse conv (gather form), KS k-steps of 16 ----------------
template <int KS>
__global__ __launch_bounds__(256) void k_conv(
    const short* __restrict__ xin, const short* __restrict__ wp,
    const int* __restrict__ nbr, const int* __restrict__ perm2d,
    const int* __restrict__ cnt, float* __restrict__ y,
    float* __restrict__ stats, int n2)
{
    const int rowlen = KS * 16;
    int wid = blockIdx.x * 4 + (threadIdx.x >> 6);
    int lane = threadIdx.x & 63;
    int nt = wid & 1;
    int rt = wid >> 1;
    int k, ck, lt;
    if (!map_tile(cnt, rt, k, ck, lt)) return;
    int m = lane & 31, half = lane >> 5;
    int slot = lt * 32 + m;
    int d = (slot < ck) ? perm2d[(size_t)k * n2 + slot] : n2;
    bool valid = d < n2;
    const bf16x8 zero8 = {0, 0, 0, 0, 0, 0, 0, 0};
    const bf16x8* wpv = (const bf16x8*)wp;
    f32x16 acc;
    #pragma unroll
    for (int i = 0; i < 16; ++i) acc[i] = 0.f;
    for (int t = 0; t < 27; ++t) {
        int s = valid ? nbr[(size_t)t * n2 + d] : n2;
        bool hit = s < n2;
        if (__ballot(hit) == 0ULL) continue;        // tap-skip: ~9.5/27 survive
        const bf16x8* ar = (const bf16x8*)(xin + (size_t)(hit ? s : 0) * rowlen + half * 8);
        const bf16x8* bp = wpv + ((size_t)t * KS * 2 + nt) * 64 + lane;
        #pragma unroll
        for (int ks = 0; ks < KS; ++ks) {
            bf16x8 a = hit ? ar[ks * 2] : zero8;
            bf16x8 b = bp[(size_t)ks * 2 * 64];
            acc = __builtin_amdgcn_mfma_f32_32x32x16_bf16(a, b, acc, 0, 0, 0);
        }
    }
    epilogue(acc, d, lane, nt, y, stats, n2);
}

// ---------------- BN finalize + materialize x = [bn_relu(yup), feats2] bf16 --
__global__ __launch_bounds__(256) void k_xmat(
    const float* __restrict__ yup, const float* __restrict__ f2,
    const float* __restrict__ gamma, const float* __restrict__ beta,
    const float* __restrict__ stats, short* __restrict__ xbf, int n2)
{
    __shared__ float sc[64], sh[64];
    int tid = threadIdx.x;
    if (tid < 64) {
        float inv = 1.0f / (float)n2;
        float mean = stats[tid] * inv;
        float var = stats[64 + tid] * inv - mean * mean;
        float s = gamma[tid] * rsqrtf(var + 1e-5f);
        sc[tid] = s;
        sh[tid] = beta[tid] - mean * s;
    }
    __syncthreads();
    long long total = (long long)n2 * 32;
    long long stride = (long long)gridDim.x * blockDim.x;
    for (long long idx = (long long)blockIdx.x * blockDim.x + tid; idx < total; idx += stride) {
        int i = (int)(idx >> 5);
        int c4 = ((int)idx & 31) * 4;
        float v0, v1, v2, v3;
        if (c4 < 64) {
            const float* src = yup + (size_t)i * 64 + c4;
            v0 = fmaxf(src[0] * sc[c4 + 0] + sh[c4 + 0], 0.f);
            v1 = fmaxf(src[1] * sc[c4 + 1] + sh[c4 + 1], 0.f);
            v2 = fmaxf(src[2] * sc[c4 + 2] + sh[c4 + 2], 0.f);
            v3 = fmaxf(src[3] * sc[c4 + 3] + sh[c4 + 3], 0.f);
        } else {
            const float* src = f2 + (size_t)i * 64 + (c4 - 64);
            v0 = src[0]; v1 = src[1]; v2 = src[2]; v3 = src[3];
        }
        short4 o;
        o.x = f2bf(v0); o.y = f2bf(v1); o.z = f2bf(v2); o.w = f2bf(v3);
        *(short4*)(xbf + (size_t)i * 128 + c4) = o;
    }
}

// ---------------- BN finalize + bf16 materialize (64-ch rows) ----------------
__global__ __launch_bounds__(256) void k_hmat(
    const float* __restrict__ y, const float* __restrict__ gamma,
    const float* __restrict__ beta, const float* __restrict__ stats,
    short* __restrict__ hbf, int n2)
{
    __shared__ float sc[64], sh[64];
    int tid = threadIdx.x;
    if (tid < 64) {
        float inv = 1.0f / (float)n2;
        float mean = stats[tid] * inv;
        float var = stats[64 + tid] * inv - mean * mean;
        float s = gamma[tid] * rsqrtf(var + 1e-5f);
        sc[tid] = s;
        sh[tid] = beta[tid] - mean * s;
    }
    __syncthreads();
    long long total = (long long)n2 * 16;
    long long stride = (long long)gridDim.x * blockDim.x;
    for (long long idx = (long long)blockIdx.x * blockDim.x + tid; idx < total; idx += stride) {
        int i = (int)(idx >> 4);
        int c4 = ((int)idx & 15) * 4;
        const float* src = y + (size_t)i * 64 + c4;
        short4 o;
        o.x = f2bf(fmaxf(src[0] * sc[c4 + 0] + sh[c4 + 0], 0.f));
        o.y = f2bf(fmaxf(src[1] * sc[c4 + 1] + sh[c4 + 1], 0.f));
        o.z = f2bf(fmaxf(src[2] * sc[c4 + 2] + sh[c4 + 2], 0.f));
        o.w = f2bf(fmaxf(src[3] * sc[c4 + 3] + sh[c4 + 3], 0.f));
        *(short4*)(hbf + (size_t)i * 64 + c4) = o;
    }
}

// ---------------- BN finalize + ReLU -> f32 output ---------------------------
__global__ __launch_bounds__(256) void k_final(
    const float* __restrict__ y, const float* __restrict__ gamma,
    const float* __restrict__ beta, const float* __restrict__ stats,
    float* __restrict__ out, int n2)
{
    __shared__ float sc[64], sh[64];
    int tid = threadIdx.x;
    if (tid < 64) {
        float inv = 1.0f / (float)n2;
        float mean = stats[tid] * inv;
        float var = stats[64 + tid] * inv - mean * mean;
        float s = gamma[tid] * rsqrtf(var + 1e-5f);
        sc[tid] = s;
        sh[tid] = beta[tid] - mean * s;
    }
    __syncthreads();
    long long total = (long long)n2 * 16;
    long long stride = (long long)gridDim.x * blockDim.x;
    for (long long idx = (long long)blockIdx.x * blockDim.x + tid; idx < total; idx += stride) {
        int i = (int)(idx >> 4);
        int c4 = ((int)idx & 15) * 4;
        const float* src = y + (size_t)i * 64 + c4;
        float4 o;
        o.x = fmaxf(src[0] * sc[c4 + 0] + sh[c4 + 0], 0.f);
        o.y = fmaxf(src[1] * sc[c4 + 1] + sh[c4 + 1], 0.f);
        o.z = fmaxf(src[2] * sc[c4 + 2] + sh[c4 + 2], 0.f);
        o.w = fmaxf(src[3] * sc[c4 + 3] + sh[c4 + 3], 0.f);
        *(float4*)(out + (size_t)i * 64 + c4) = o;
    }
}

extern "C" void kernel_launch(void* const* d_in, const int* in_sizes, int n_in,
                              void* d_out, int out_size, void* d_ws, size_t ws_size,
                              hipStream_t stream)
{
    const float* feats1   = (const float*)d_in[0];
    const float* feats2   = (const float*)d_in[1];
    const float* w_up     = (const float*)d_in[2];
    const float* gamma_up = (const float*)d_in[3];
    const float* beta_up  = (const float*)d_in[4];
    const float* w1       = (const float*)d_in[5];
    const float* gamma1   = (const float*)d_in[6];
    const float* beta1    = (const float*)d_in[7];
    const float* w2       = (const float*)d_in[8];
    const float* gamma2   = (const float*)d_in[9];
    const float* beta2    = (const float*)d_in[10];
    const int* up_src     = (const int*)d_in[11];
    const int* up_kidx    = (const int*)d_in[12];
    const int* nbr_src    = (const int*)d_in[13];
    // d_in[14] nbr_dst unused: construction guarantees nbr_dst[t,i] ∈ {i, N2}

    int n1 = in_sizes[0] / 128;
    int n2 = in_sizes[1] / 64;

    char* p = (char*)d_ws;
    auto alloc = [&](size_t bytes) {
        char* r = p;
        p += (bytes + 255) & ~(size_t)255;
        return r;
    };
    int*   cnt    = (int*)alloc(8 * 4);
    float* stats  = (float*)alloc(384 * 4);        // [up|c1|c2] x (sum64, sq64)
    short* wupp   = (short*)alloc((size_t)65536 * 2);
    short* w1p    = (short*)alloc((size_t)221184 * 2);
    short* w2p    = (short*)alloc((size_t)110592 * 2);
    short* f1bf   = (short*)alloc((size_t)n1 * 128 * 2);
    int*   perm2d = (int*)alloc((size_t)8 * n2 * 4);
    float* yup    = (float*)alloc((size_t)n2 * 64 * 4);
    short* xbf    = (short*)alloc((size_t)n2 * 128 * 2);
    float* y1     = (float*)alloc((size_t)n2 * 64 * 4);
    short* hbf    = (short*)alloc((size_t)n2 * 64 * 2);
    float* y2     = yup;  // yup dead after k_xmat; reuse for conv2 output

    long long packTotal = 65536 + 221184 + 110592 + (long long)n1 * 128;
    int packBlocks = (int)((packTotal + 255) / 256);
    k_pack<<<packBlocks, 256, 0, stream>>>(w_up, w1, w2, feats1, wupp, w1p, w2p,
                                           f1bf, cnt, stats, n1);
    k_scatter<<<(n2 + 255) / 256, 256, 0, stream>>>(up_kidx, cnt, perm2d, n2);

    int rowTilesMax = (n2 + 31) / 32 + 8;          // padded buckets upper bound
    int convBlocks  = (2 * rowTilesMax + 3) / 4;   // 2 n-tiles/row-tile, 4 waves/blk
    int ewBlocks32  = (int)(((long long)n2 * 32 + 255) / 256);
    int ewBlocks16  = (int)(((long long)n2 * 16 + 255) / 256);

    k_up<<<convBlocks, 256, 0, stream>>>(f1bf, wupp, up_src, perm2d, cnt, yup,
                                         stats, n2);
    k_xmat<<<ewBlocks32, 256, 0, stream>>>(yup, feats2, gamma_up, beta_up, stats,
                                           xbf, n2);
    k_conv<8><<<convBlocks, 256, 0, stream>>>(xbf, w1p, nbr_src, perm2d, cnt, y1,
                                              stats + 128, n2);
    k_hmat<<<ewBlocks16, 256, 0, stream>>>(y1, gamma1, beta1, stats + 128, hbf, n2);
    k_conv<4><<<convBlocks, 256, 0, stream>>>(hbf, w2p, nbr_src, perm2d, cnt, y2,
                                              stats + 256, n2);
    k_final<<<ewBlocks16, 256, 0, stream>>>(y2, gamma2, beta2, stats + 256,
                                            (float*)d_out, n2);
}